// Round 18
// baseline (333.581 us; speedup 1.0000x reference)
//
#include <hip/hip_runtime.h>
#include <hip/hip_bf16.h>

typedef __attribute__((ext_vector_type(8))) short bf16x8;
typedef __attribute__((ext_vector_type(4))) float f32x4;
typedef float f32x4u __attribute__((ext_vector_type(4), aligned(4))); // x rows only 4B-aligned
typedef __attribute__((ext_vector_type(4))) short short4v;
typedef unsigned short ushort_t;

#define CC 120
#define LL 469
#define HH 64

constexpr int NBATCH = 1024;
constexpr int KSTEPS = 15;

// DIAGNOSTIC ROUND: template<MODE> ablation.
//  MODE 0 = full kernel (r16, unchanged) -> d_out
//  MODE 1 = phase-1 only, x4 reps, acc dumped to ws   (times the QKV GEMM)
//  MODE 2 = phase-2+epilogue only, x4 reps, out -> ws (times attention+epilogue)
// r16 base: Wl[3][8192 shorts] triple buffer, X in named regs, depth-2, vmcnt(8).
constexpr int WB_SHORTS   = 8192;
constexpr int SMEM_BYTES  = 49152;
constexpr int WIMG_SHORTS = KSTEPS * WB_SHORTS;    // 122880
constexpr int WIMG_BYTES  = WIMG_SHORTS * 2;       // 245760

__device__ __forceinline__ ushort_t f2bf(float f) {
  __hip_bfloat16 h = __float2bfloat16(f);
  return __builtin_bit_cast(ushort_t, h);
}

__device__ __forceinline__ void gload_lds16(const void* g, void* l) {
  __builtin_amdgcn_global_load_lds(
      (const __attribute__((address_space(1))) unsigned int*)g,
      (__attribute__((address_space(3))) unsigned int*)l, 16, 0, 0);
}

__device__ __forceinline__ char* sptr(char* base, int row, int stride, int byteoff) {
  return base + row * stride + (byteoff ^ ((row & 7) << 4));
}

__global__ void prep_w(const float* __restrict__ Wk, const float* __restrict__ Wq,
                       const float* __restrict__ Wv, ushort_t* __restrict__ wimg) {
  int idx = blockIdx.x * 256 + threadIdx.x; // 122880 exactly (480 blocks)
  int t = idx / WB_SHORTS;
  int r = idx % WB_SHORTS;
  int col = r / 40, kk = r % 40;
  float v = 0.f;
  if (r < 192 * 40 && kk < 32) {
    int kb = (t == 14) ? 437 : t * 32;
    int k = kb + kk;
    bool live = (k < LL) && (t < 14 || k >= 448);
    if (live) {
      int wsel = col >> 6, h = col & 63;
      const float* wp = (wsel == 0) ? Wk : (wsel == 1) ? Wq : Wv;
      v = wp[(size_t)k * HH + h];
    }
  }
  wimg[idx] = f2bf(v);
}

#define XISSUE(T, X0, X1, X2, X3)                                              \
  {                                                                            \
    const int _k = (((T) == 14) ? 437 : (T) * 32) + lg * 8;                    \
    X0 = *(const f32x4u*)(xr0 + _k);                                           \
    X1 = *(const f32x4u*)(xr0 + _k + 4);                                       \
    X2 = *(const f32x4u*)(xr1c + _k);                                          \
    X3 = *(const f32x4u*)(xr1c + _k + 4);                                      \
  }
#define WISSUE(T)                                                              \
  {                                                                            \
    const char* _src = (const char*)(wimg + (size_t)(T) * WB_SHORTS);          \
    char* _dst = (char*)(Wl + ((T) % 3) * WB_SHORTS);                          \
    _Pragma("unroll")                                                          \
    for (int _i = 0; _i < 4; ++_i) {                                           \
      int _c = wv + 4 * _i;                                                    \
      gload_lds16(_src + _c * 1024 + lane * 16, _dst + _c * 1024);             \
    }                                                                          \
  }
#define ENDREGION(N)                                                           \
  {                                                                            \
    __builtin_amdgcn_sched_barrier(0);                                         \
    asm volatile("s_waitcnt vmcnt(" #N ")" ::: "memory");                      \
    __builtin_amdgcn_sched_barrier(0);                                         \
    __builtin_amdgcn_s_barrier();                                              \
    __builtin_amdgcn_sched_barrier(0);                                         \
  }
#define COMPUTE(T, X0, X1, X2, X3)                                             \
  {                                                                            \
    const ushort_t* _wb = Wl + ((T) % 3) * WB_SHORTS;                          \
    bf16x8 _a0, _a1;                                                           \
    _Pragma("unroll")                                                          \
    for (int _j = 0; _j < 4; ++_j) {                                           \
      _a0[_j] = (short)f2bf(X0[_j]); _a0[4 + _j] = (short)f2bf(X1[_j]);        \
      _a1[_j] = (short)f2bf(X2[_j]); _a1[4 + _j] = (short)f2bf(X3[_j]);        \
    }                                                                          \
    _Pragma("unroll")                                                          \
    for (int _n = 0; _n < 12; ++_n) {                                          \
      bf16x8 _b = *(const bf16x8*)(_wb + (_n * 16 + lr) * 40 + lg * 8);        \
      acc[0][_n] = __builtin_amdgcn_mfma_f32_16x16x32_bf16(_a0, _b, acc[0][_n], 0, 0, 0); \
      acc[1][_n] = __builtin_amdgcn_mfma_f32_16x16x32_bf16(_a1, _b, acc[1][_n], 0, 0, 0); \
    }                                                                          \
  }

template <int MODE, bool WIMG>
__global__ __launch_bounds__(256, 2)
void fused_regional_head(const float* __restrict__ x,
                         const float* __restrict__ Wk,
                         const float* __restrict__ Wq,
                         const float* __restrict__ Wv,
                         const ushort_t* __restrict__ wimg,
                         float* __restrict__ outp) {
  __shared__ char smem[SMEM_BYTES];
  const int tid = threadIdx.x;
  const int lane = tid & 63;
  const int wv = tid >> 6;
  const int lr = lane & 15;
  const int lg = lane >> 4;
  const int batch = blockIdx.x;
  const size_t xbase = (size_t)batch * CC * LL;

  ushort_t* Wl = (ushort_t*)smem;

  const int row0 = wv * 32 + lr;
  const int row1 = wv * 32 + 16 + lr;
  const int row1c = (row1 < CC) ? row1 : (CC - 1);
  const float* xr0  = x + xbase + (size_t)row0 * LL;
  const float* xr1c = x + xbase + (size_t)row1c * LL;

  f32x4 acc[2][12];
#pragma unroll
  for (int m = 0; m < 2; ++m)
#pragma unroll
    for (int n = 0; n < 12; ++n) acc[m][n] = (f32x4){0.f, 0.f, 0.f, 0.f};

  // ---------------- phase 1 (MODE 0 once, MODE 1 x4, MODE 2 skip) ----------------
  if constexpr (MODE != 2) {
    if constexpr (WIMG) {
#pragma unroll 1
      for (int rep = 0; rep < (MODE == 1 ? 4 : 1); ++rep) {
        f32x4u xA0, xA1, xA2, xA3, xB0, xB1, xB2, xB3, xC0, xC1, xC2, xC3;
        WISSUE(0); XISSUE(0, xA0, xA1, xA2, xA3);
        WISSUE(1); XISSUE(1, xB0, xB1, xB2, xB3);
        ENDREGION(8);
#pragma unroll
        for (int tt = 0; tt < 4; ++tt) {
          const int t = 3 * tt;
          WISSUE(t + 2); XISSUE(t + 2, xC0, xC1, xC2, xC3);
          COMPUTE(t, xA0, xA1, xA2, xA3);
          ENDREGION(8);
          WISSUE(t + 3); XISSUE(t + 3, xA0, xA1, xA2, xA3);
          COMPUTE(t + 1, xB0, xB1, xB2, xB3);
          ENDREGION(8);
          WISSUE(t + 4); XISSUE(t + 4, xB0, xB1, xB2, xB3);
          COMPUTE(t + 2, xC0, xC1, xC2, xC3);
          ENDREGION(8);
        }
        WISSUE(14); XISSUE(14, xC0, xC1, xC2, xC3);
        COMPUTE(12, xA0, xA1, xA2, xA3);
        ENDREGION(8);
        COMPUTE(13, xB0, xB1, xB2, xB3);
        ENDREGION(0);
        COMPUTE(14, xC0, xC1, xC2, xC3);
        if (MODE == 1) __syncthreads();
      }
    } else {
      for (int t = 0; t < KSTEPS; ++t) {
        const int kb = (t == 14) ? 437 : t * 32;
        f32x4u x0 = *(const f32x4u*)(xr0 + kb + lg * 8);
        f32x4u x1 = *(const f32x4u*)(xr0 + kb + lg * 8 + 4);
        f32x4u x2 = *(const f32x4u*)(xr1c + kb + lg * 8);
        f32x4u x3 = *(const f32x4u*)(xr1c + kb + lg * 8 + 4);
        bf16x8 a0, a1;
#pragma unroll
        for (int j = 0; j < 4; ++j) {
          a0[j] = (short)f2bf(x0[j]); a0[4 + j] = (short)f2bf(x1[j]);
          a1[j] = (short)f2bf(x2[j]); a1[4 + j] = (short)f2bf(x3[j]);
        }
#pragma unroll
        for (int n = 0; n < 12; ++n) {
          int col = n * 16 + lr;
          int wsel = col >> 6, h = col & 63;
          const float* wp = (wsel == 0) ? Wk : (wsel == 1) ? Wq : Wv;
          bf16x8 b;
#pragma unroll
          for (int j = 0; j < 8; ++j) {
            int k = kb + lg * 8 + j;
            bool live = (k < LL) && (t < 14 || k >= 448);
            b[j] = (short)f2bf(live ? wp[(size_t)k * HH + h] : 0.f);
          }
          acc[0][n] = __builtin_amdgcn_mfma_f32_16x16x32_bf16(a0, b, acc[0][n], 0, 0, 0);
          acc[1][n] = __builtin_amdgcn_mfma_f32_16x16x32_bf16(a1, b, acc[1][n], 0, 0, 0);
        }
      }
    }
  } else {
    // MODE 2: seed acc from one global read (data-dependent, not DCE-able)
    float seed = x[xbase + tid];
#pragma unroll
    for (int m = 0; m < 2; ++m)
#pragma unroll
      for (int n = 0; n < 12; ++n)
        acc[m][n] = (f32x4){seed, seed * 0.25f, -seed, seed + 2.0f};
  }

  if constexpr (MODE == 1) {
    // dump acc (keeps phase-1 live), exit
    size_t base = ((size_t)batch * 256 + tid) * 96;
#pragma unroll
    for (int m = 0; m < 2; ++m)
#pragma unroll
      for (int n = 0; n < 12; ++n)
        *(f32x4*)(outp + base + (m * 12 + n) * 4) = acc[m][n];
    return;
  }

  // ---------------- phase 2 + epilogue (MODE 0 once, MODE 2 x4) ----------------
  char* Qb = smem;
  char* Kb = smem + 16384;
  char* Vb = smem + 32768;
  char* Pb = smem;
#pragma unroll 1
  for (int rep = 0; rep < (MODE == 2 ? 4 : 1); ++rep) {
    __syncthreads(); // staging region dead / prev rep done
#pragma unroll
    for (int mt = 0; mt < 2; ++mt) {
#pragma unroll
      for (int r = 0; r < 4; ++r) {
        int row = wv * 32 + mt * 16 + lg * 4 + r;
#pragma unroll
        for (int n = 0; n < 4; ++n) {
          *(ushort_t*)sptr(Kb, row, 128, (n * 16 + lr) * 2) = f2bf(acc[mt][n][r]);
          *(ushort_t*)sptr(Qb, row, 128, (n * 16 + lr) * 2) = f2bf(acc[mt][4 + n][r]);
        }
      }
#pragma unroll
      for (int n = 0; n < 4; ++n) {
        short4v pk;
#pragma unroll
        for (int r = 0; r < 4; ++r) pk[r] = (short)f2bf(acc[mt][8 + n][r]);
        *(short4v*)sptr(Vb, n * 16 + lr, 256, (wv * 32 + mt * 16 + lg * 4) * 2) = pk;
      }
    }
    __syncthreads();

    f32x4 accw[2][8];
#pragma unroll
    for (int m = 0; m < 2; ++m)
#pragma unroll
      for (int n = 0; n < 8; ++n) accw[m][n] = (f32x4){0.f, 0.f, 0.f, 0.f};
#pragma unroll
    for (int ks = 0; ks < 2; ++ks) {
      bf16x8 a0 = *(const bf16x8*)sptr(Qb, wv * 32 + lr, 128, ks * 64 + lg * 16);
      bf16x8 a1 = *(const bf16x8*)sptr(Qb, wv * 32 + 16 + lr, 128, ks * 64 + lg * 16);
#pragma unroll
      for (int n = 0; n < 8; ++n) {
        bf16x8 b = *(const bf16x8*)sptr(Kb, n * 16 + lr, 128, ks * 64 + lg * 16);
        accw[0][n] = __builtin_amdgcn_mfma_f32_16x16x32_bf16(a0, b, accw[0][n], 0, 0, 0);
        accw[1][n] = __builtin_amdgcn_mfma_f32_16x16x32_bf16(a1, b, accw[1][n], 0, 0, 0);
      }
    }
    __syncthreads();

#pragma unroll
    for (int mt = 0; mt < 2; ++mt)
#pragma unroll
      for (int r = 0; r < 4; ++r) {
        float l[8];
        float m = -1e30f;
#pragma unroll
        for (int n = 0; n < 8; ++n) {
          float v = accw[mt][n][r] * 0.125f;
          if (n == 7 && lr >= 8) v = -1e30f;
          l[n] = v;
          m = fmaxf(m, v);
        }
#pragma unroll
        for (int off = 1; off < 16; off <<= 1) m = fmaxf(m, __shfl_xor(m, off));
        float s = 0.f;
#pragma unroll
        for (int n = 0; n < 8; ++n) {
          float p = __expf(l[n] - m);
          l[n] = p;
          s += p;
        }
#pragma unroll
        for (int off = 1; off < 16; off <<= 1) s += __shfl_xor(s, off);
        float inv = 1.f / s;
        int row = wv * 32 + mt * 16 + lg * 4 + r;
#pragma unroll
        for (int n = 0; n < 8; ++n)
          *(ushort_t*)sptr(Pb, row, 256, (n * 16 + lr) * 2) = f2bf(l[n] * inv);
      }

    f32x4 acco[2][4];
#pragma unroll
    for (int m = 0; m < 2; ++m)
#pragma unroll
      for (int n = 0; n < 4; ++n) acco[m][n] = (f32x4){0.f, 0.f, 0.f, 0.f};
#pragma unroll
    for (int ks = 0; ks < 4; ++ks) {
      bf16x8 a0 = *(const bf16x8*)sptr(Pb, wv * 32 + lr, 256, ks * 64 + lg * 16);
      bf16x8 a1 = *(const bf16x8*)sptr(Pb, wv * 32 + 16 + lr, 256, ks * 64 + lg * 16);
#pragma unroll
      for (int n = 0; n < 4; ++n) {
        bf16x8 b = *(const bf16x8*)sptr(Vb, n * 16 + lr, 256, ks * 64 + lg * 16);
        acco[0][n] = __builtin_amdgcn_mfma_f32_16x16x32_bf16(a0, b, acco[0][n], 0, 0, 0);
        acco[1][n] = __builtin_amdgcn_mfma_f32_16x16x32_bf16(a1, b, acco[1][n], 0, 0, 0);
      }
    }

    __syncthreads();
    float* Ob = (float*)smem;
#pragma unroll
    for (int mt = 0; mt < 2; ++mt)
#pragma unroll
      for (int r = 0; r < 4; ++r) {
        int row = wv * 32 + mt * 16 + lg * 4 + r;
        if (row < CC) {
#pragma unroll
          for (int n = 0; n < 4; ++n)
            Ob[row * 68 + n * 16 + lr] = acco[mt][n][r];
        }
      }
    __syncthreads();
    const size_t obase = (size_t)batch * CC * HH;
#pragma unroll
    for (int i = 0; i < 8; ++i) {
      int idx = i * 256 + tid;
      if (idx < 1920) {
        int row = idx >> 4;
        int c4 = (idx & 15) * 4;
        f32x4 v = *(const f32x4*)(Ob + row * 68 + c4);
        *(f32x4*)(outp + obase + (size_t)idx * 4) = v;
      }
    }
  }
}

extern "C" void kernel_launch(void* const* d_in, const int* in_sizes, int n_in,
                              void* d_out, int out_size, void* d_ws, size_t ws_size,
                              hipStream_t stream) {
  (void)in_sizes; (void)n_in; (void)out_size;
  const float* x  = (const float*)d_in[0];
  const float* Wk = (const float*)d_in[1];
  const float* Wq = (const float*)d_in[2];
  const float* Wv = (const float*)d_in[3];
  float* out = (float*)d_out;
  if (ws_size >= (size_t)WIMG_BYTES && d_ws != nullptr) {
    ushort_t* wimg = (ushort_t*)d_ws;
    prep_w<<<480, 256, 0, stream>>>(Wk, Wq, Wv, wimg);
    if (ws_size >= ((size_t)320 << 20)) {
      // diagnostic ablation dispatches (outputs to ws; real kernel runs last)
      float* dump1 = (float*)((char*)d_ws + ((size_t)4 << 20));
      float* dump2 = (float*)((char*)d_ws + ((size_t)256 << 20));
      fused_regional_head<1, true><<<NBATCH, 256, 0, stream>>>(x, Wk, Wq, Wv, wimg, dump1);
      fused_regional_head<2, true><<<NBATCH, 256, 0, stream>>>(x, Wk, Wq, Wv, wimg, dump2);
    }
    fused_regional_head<0, true><<<NBATCH, 256, 0, stream>>>(x, Wk, Wq, Wv, wimg, out);
  } else {
    fused_regional_head<0, false><<<NBATCH, 256, 0, stream>>>(x, Wk, Wq, Wv, nullptr, out);
  }
}

// Round 19
// 122.243 us; speedup vs baseline: 2.7288x; 2.7288x over previous
//
#include <hip/hip_runtime.h>
#include <hip/hip_bf16.h>

typedef __attribute__((ext_vector_type(8))) short bf16x8;
typedef __attribute__((ext_vector_type(4))) float f32x4;
typedef float f32x4u __attribute__((ext_vector_type(4), aligned(4))); // x rows only 4B-aligned
typedef __attribute__((ext_vector_type(4))) short short4v;
typedef unsigned short ushort_t;

#define CC 120
#define LL 469
#define HH 64

constexpr int NBATCH = 1024;
constexpr int KSTEPS = 15;

// ---- structure (r18 ablation: phase1 ~63us, phase2 ~2.5us) ----
// phase 1: NO LDS, NO barriers. X -> named registers (depth-1 prefetch).
//          W B-fragments -> direct coalesced dwordx4 from L2-resident fragment
//          image (184 KB), consumed immediately by MFMA. Waves fully decoupled.
// phase 2: r16 verbatim: Qb @0 (16K, [128]x128B swz), Kb @16384, Vb @32768
//          ([64]x256B swz); Pb @0 aliases Q+K after QK^T; epilogue Ob f32 [120][68] @0
constexpr int SMEM_BYTES  = 49152;                  // phase-2 only
constexpr int WIMG_SHORTS = KSTEPS * 12 * 64 * 8;   // 92160
constexpr int WIMG_BYTES  = WIMG_SHORTS * 2;        // 184320

__device__ __forceinline__ ushort_t f2bf(float f) {
  __hip_bfloat16 h = __float2bfloat16(f);
  return __builtin_bit_cast(ushort_t, h);
}

// XOR-swizzled LDS address for phase-2 tiles
__device__ __forceinline__ char* sptr(char* base, int row, int stride, int byteoff) {
  return base + row * stride + (byteoff ^ ((row & 7) << 4));
}

// W image in MFMA fragment order:
// wimg[((t*12+n)*64+lane)*8+j] = Wcat[kb(t)+ (lane>>4)*8 + j][n*16 + (lane&15)]
// kb(t) = t*32 for t<14, 437 for t=14 (shifted window; k<448 zeroed -- those k
// are covered by step 13, and zero B-frags null the overlap contributions).
__global__ void prep_w(const float* __restrict__ Wk, const float* __restrict__ Wq,
                       const float* __restrict__ Wv, ushort_t* __restrict__ wimg) {
  int idx = blockIdx.x * 256 + threadIdx.x; // 92160 exactly (360 blocks)
  int j = idx & 7;
  int lane = (idx >> 3) & 63;
  int tn = idx >> 9;
  int n = tn % 12;
  int t = tn / 12;
  int lr = lane & 15, lg = lane >> 4;
  int kb = (t == 14) ? 437 : t * 32;
  int k = kb + lg * 8 + j;
  int col = n * 16 + lr;
  float v = 0.f;
  bool live = (k < LL) && (t < 14 || k >= 448);
  if (live) {
    int wsel = col >> 6, h = col & 63;
    const float* wp = (wsel == 0) ? Wk : (wsel == 1) ? Wq : Wv;
    v = wp[(size_t)k * HH + h];
  }
  wimg[idx] = f2bf(v);
}

// X A-fragment loads: 4 vector loads into NAMED registers (never address-taken)
#define XISSUE(T, X0, X1, X2, X3)                                              \
  {                                                                            \
    const int _k = (((T) == 14) ? 437 : (T) * 32) + lg * 8;                    \
    X0 = *(const f32x4u*)(xr0 + _k);                                           \
    X1 = *(const f32x4u*)(xr0 + _k + 4);                                       \
    X2 = *(const f32x4u*)(xr1c + _k);                                          \
    X3 = *(const f32x4u*)(xr1c + _k + 4);                                      \
  }
// compute step T: 12 B-frags direct from L2 image, consumed immediately
#define COMPUTE(T, X0, X1, X2, X3)                                             \
  {                                                                            \
    bf16x8 _a0, _a1;                                                           \
    _Pragma("unroll")                                                          \
    for (int _j = 0; _j < 4; ++_j) {                                           \
      _a0[_j] = (short)f2bf(X0[_j]); _a0[4 + _j] = (short)f2bf(X1[_j]);        \
      _a1[_j] = (short)f2bf(X2[_j]); _a1[4 + _j] = (short)f2bf(X3[_j]);        \
    }                                                                          \
    const ushort_t* _wt = wfrag + (size_t)(T) * 6144;                          \
    _Pragma("unroll")                                                          \
    for (int _n = 0; _n < 12; ++_n) {                                          \
      bf16x8 _b = *(const bf16x8*)(_wt + _n * 512);                            \
      acc[0][_n] = __builtin_amdgcn_mfma_f32_16x16x32_bf16(_a0, _b, acc[0][_n], 0, 0, 0); \
      acc[1][_n] = __builtin_amdgcn_mfma_f32_16x16x32_bf16(_a1, _b, acc[1][_n], 0, 0, 0); \
    }                                                                          \
  }

template <bool WIMG>
__global__ __launch_bounds__(256, 2)
void fused_regional_head(const float* __restrict__ x,
                         const float* __restrict__ Wk,
                         const float* __restrict__ Wq,
                         const float* __restrict__ Wv,
                         const ushort_t* __restrict__ wimg,
                         float* __restrict__ out) {
  __shared__ char smem[SMEM_BYTES];
  const int tid = threadIdx.x;
  const int lane = tid & 63;
  const int wv = tid >> 6;   // wave 0..3, owns rows 32*wv .. 32*wv+31
  const int lr = lane & 15;
  const int lg = lane >> 4;
  const int batch = blockIdx.x;
  const size_t xbase = (size_t)batch * CC * LL;

  const int row0 = wv * 32 + lr;                    // < 120 always
  const int row1 = wv * 32 + 16 + lr;               // 120..127 for wave3 lr>=8
  const int row1c = (row1 < CC) ? row1 : (CC - 1);  // clamp; garbage masked downstream
  const float* xr0  = x + xbase + (size_t)row0 * LL;
  const float* xr1c = x + xbase + (size_t)row1c * LL;
  const ushort_t* wfrag = wimg + (size_t)lane * 8;  // this lane's fragment base

  // ---------------- phase 1: QKV = X @ [Wk|Wq|Wv] -- no LDS, no barriers ----------------
  f32x4 acc[2][12];
#pragma unroll
  for (int m = 0; m < 2; ++m)
#pragma unroll
    for (int n = 0; n < 12; ++n) acc[m][n] = (f32x4){0.f, 0.f, 0.f, 0.f};

  if constexpr (WIMG) {
    f32x4u xA0, xA1, xA2, xA3, xB0, xB1, xB2, xB3;
    XISSUE(0, xA0, xA1, xA2, xA3);
#pragma unroll
    for (int tt = 0; tt < 7; ++tt) {
      const int t = 2 * tt;
      XISSUE(t + 1, xB0, xB1, xB2, xB3);
      COMPUTE(t, xA0, xA1, xA2, xA3);
      XISSUE(t + 2, xA0, xA1, xA2, xA3);
      COMPUTE(t + 1, xB0, xB1, xB2, xB3);
    }
    COMPUTE(14, xA0, xA1, xA2, xA3);
  } else {
    // slow fallback (unused when ws present): W frags gathered inline
    for (int t = 0; t < KSTEPS; ++t) {
      const int kb = (t == 14) ? 437 : t * 32;
      f32x4u x0 = *(const f32x4u*)(xr0 + kb + lg * 8);
      f32x4u x1 = *(const f32x4u*)(xr0 + kb + lg * 8 + 4);
      f32x4u x2 = *(const f32x4u*)(xr1c + kb + lg * 8);
      f32x4u x3 = *(const f32x4u*)(xr1c + kb + lg * 8 + 4);
      bf16x8 a0, a1;
#pragma unroll
      for (int j = 0; j < 4; ++j) {
        a0[j] = (short)f2bf(x0[j]); a0[4 + j] = (short)f2bf(x1[j]);
        a1[j] = (short)f2bf(x2[j]); a1[4 + j] = (short)f2bf(x3[j]);
      }
#pragma unroll
      for (int n = 0; n < 12; ++n) {
        int col = n * 16 + lr;
        int wsel = col >> 6, h = col & 63;
        const float* wp = (wsel == 0) ? Wk : (wsel == 1) ? Wq : Wv;
        bf16x8 b;
#pragma unroll
        for (int j = 0; j < 8; ++j) {
          int k = kb + lg * 8 + j;
          bool live = (k < LL) && (t < 14 || k >= 448);
          b[j] = (short)f2bf(live ? wp[(size_t)k * HH + h] : 0.f);
        }
        acc[0][n] = __builtin_amdgcn_mfma_f32_16x16x32_bf16(a0, b, acc[0][n], 0, 0, 0);
        acc[1][n] = __builtin_amdgcn_mfma_f32_16x16x32_bf16(a1, b, acc[1][n], 0, 0, 0);
      }
    }
  }
  __syncthreads(); // phase-2 tiles take over LDS

  // ---------------- write Q,K,V (bf16, swizzled) ----------------
  char* Qb = smem;
  char* Kb = smem + 16384;
  char* Vb = smem + 32768;
  char* Pb = smem;
#pragma unroll
  for (int mt = 0; mt < 2; ++mt) {
#pragma unroll
    for (int r = 0; r < 4; ++r) {
      int row = wv * 32 + mt * 16 + lg * 4 + r;
#pragma unroll
      for (int n = 0; n < 4; ++n) {
        *(ushort_t*)sptr(Kb, row, 128, (n * 16 + lr) * 2) = f2bf(acc[mt][n][r]);
        *(ushort_t*)sptr(Qb, row, 128, (n * 16 + lr) * 2) = f2bf(acc[mt][4 + n][r]);
      }
    }
    // V^T packed: 4 consecutive d-rows -> ds_write_b64
#pragma unroll
    for (int n = 0; n < 4; ++n) {
      short4v pk;
#pragma unroll
      for (int r = 0; r < 4; ++r) pk[r] = (short)f2bf(acc[mt][8 + n][r]);
      *(short4v*)sptr(Vb, n * 16 + lr, 256, (wv * 32 + mt * 16 + lg * 4) * 2) = pk;
    }
  }
  __syncthreads();

  // ---------------- QK^T ----------------
  f32x4 accw[2][8];
#pragma unroll
  for (int m = 0; m < 2; ++m)
#pragma unroll
    for (int n = 0; n < 8; ++n) accw[m][n] = (f32x4){0.f, 0.f, 0.f, 0.f};
#pragma unroll
  for (int ks = 0; ks < 2; ++ks) {
    bf16x8 a0 = *(const bf16x8*)sptr(Qb, wv * 32 + lr, 128, ks * 64 + lg * 16);
    bf16x8 a1 = *(const bf16x8*)sptr(Qb, wv * 32 + 16 + lr, 128, ks * 64 + lg * 16);
#pragma unroll
    for (int n = 0; n < 8; ++n) {
      bf16x8 b = *(const bf16x8*)sptr(Kb, n * 16 + lr, 128, ks * 64 + lg * 16);
      accw[0][n] = __builtin_amdgcn_mfma_f32_16x16x32_bf16(a0, b, accw[0][n], 0, 0, 0);
      accw[1][n] = __builtin_amdgcn_mfma_f32_16x16x32_bf16(a1, b, accw[1][n], 0, 0, 0);
    }
  }
  __syncthreads(); // all done reading Q/K before P overwrites

  // ---------------- softmax (wave-parallel over 16-lane col groups) ----------------
#pragma unroll
  for (int mt = 0; mt < 2; ++mt)
#pragma unroll
    for (int r = 0; r < 4; ++r) {
      float l[8];
      float m = -1e30f;
#pragma unroll
      for (int n = 0; n < 8; ++n) {
        float v = accw[mt][n][r] * 0.125f;
        if (n == 7 && lr >= 8) v = -1e30f; // col = 112+lr >= 120 masked
        l[n] = v;
        m = fmaxf(m, v);
      }
#pragma unroll
      for (int off = 1; off < 16; off <<= 1) m = fmaxf(m, __shfl_xor(m, off));
      float s = 0.f;
#pragma unroll
      for (int n = 0; n < 8; ++n) {
        float p = __expf(l[n] - m);
        l[n] = p;
        s += p;
      }
#pragma unroll
      for (int off = 1; off < 16; off <<= 1) s += __shfl_xor(s, off);
      float inv = 1.f / s;
      int row = wv * 32 + mt * 16 + lg * 4 + r;
#pragma unroll
      for (int n = 0; n < 8; ++n)
        *(ushort_t*)sptr(Pb, row, 256, (n * 16 + lr) * 2) = f2bf(l[n] * inv);
    }
  // no barrier: each wave reads only its own P rows; V covered by barrier above

  // ---------------- out = P @ V ----------------
  f32x4 acco[2][4];
#pragma unroll
  for (int m = 0; m < 2; ++m)
#pragma unroll
    for (int n = 0; n < 4; ++n) acco[m][n] = (f32x4){0.f, 0.f, 0.f, 0.f};
#pragma unroll
  for (int ks = 0; ks < 4; ++ks) {
    bf16x8 a0 = *(const bf16x8*)sptr(Pb, wv * 32 + lr, 256, ks * 64 + lg * 16);
    bf16x8 a1 = *(const bf16x8*)sptr(Pb, wv * 32 + 16 + lr, 256, ks * 64 + lg * 16);
#pragma unroll
    for (int n = 0; n < 4; ++n) {
      bf16x8 b = *(const bf16x8*)sptr(Vb, n * 16 + lr, 256, ks * 64 + lg * 16);
      acco[0][n] = __builtin_amdgcn_mfma_f32_16x16x32_bf16(a0, b, acco[0][n], 0, 0, 0);
      acco[1][n] = __builtin_amdgcn_mfma_f32_16x16x32_bf16(a1, b, acco[1][n], 0, 0, 0);
    }
  }

  // ---------------- epilogue: LDS transpose -> float4 coalesced stores ----------------
  __syncthreads(); // P/V dead
  float* Ob = (float*)smem; // [120][68] f32
#pragma unroll
  for (int mt = 0; mt < 2; ++mt)
#pragma unroll
    for (int r = 0; r < 4; ++r) {
      int row = wv * 32 + mt * 16 + lg * 4 + r;
      if (row < CC) {
#pragma unroll
        for (int n = 0; n < 4; ++n)
          Ob[row * 68 + n * 16 + lr] = acco[mt][n][r];
      }
    }
  __syncthreads();
  const size_t obase = (size_t)batch * CC * HH;
#pragma unroll
  for (int i = 0; i < 8; ++i) {
    int idx = i * 256 + tid; // float4 index, 1920 total
    if (idx < 1920) {
      int row = idx >> 4;
      int c4 = (idx & 15) * 4;
      f32x4 v = *(const f32x4*)(Ob + row * 68 + c4);
      *(f32x4*)(out + obase + (size_t)idx * 4) = v;
    }
  }
}

extern "C" void kernel_launch(void* const* d_in, const int* in_sizes, int n_in,
                              void* d_out, int out_size, void* d_ws, size_t ws_size,
                              hipStream_t stream) {
  (void)in_sizes; (void)n_in; (void)out_size;
  const float* x  = (const float*)d_in[0];
  const float* Wk = (const float*)d_in[1];
  const float* Wq = (const float*)d_in[2];
  const float* Wv = (const float*)d_in[3];
  float* out = (float*)d_out;
  if (ws_size >= (size_t)WIMG_BYTES && d_ws != nullptr) {
    ushort_t* wimg = (ushort_t*)d_ws;
    prep_w<<<360, 256, 0, stream>>>(Wk, Wq, Wv, wimg);
    fused_regional_head<true><<<NBATCH, 256, 0, stream>>>(x, Wk, Wq, Wv, wimg, out);
  } else {
    fused_regional_head<false><<<NBATCH, 256, 0, stream>>>(x, Wk, Wq, Wv, nullptr, out);
  }
}